// Round 4
// baseline (41780.243 us; speedup 1.0000x reference)
//
#include <hip/hip_runtime.h>

#define SCOPE_AGENT __HIP_MEMORY_SCOPE_AGENT

using half8  = __attribute__((ext_vector_type(8))) _Float16;
using f32x4  = __attribute__((ext_vector_type(4))) float;
typedef unsigned long long ull;

static constexpr int TT  = 2048;   // time steps
static constexpr int NB  = 16;     // batch
static constexpr int SS  = 512;    // state dim
static constexpr int NCH = 32;     // column chunks of 16
static constexpr int SPIN_BOUND = 1 << 17;  // sticky bailout: hang -> fast wrong answer

__device__ __forceinline__ float bits2f(unsigned u) { return __builtin_bit_cast(float, u); }

// -------------------- fill --------------------
__global__ void fill_kernel(unsigned int* __restrict__ p, unsigned int v, int n) {
    int i = blockIdx.x * blockDim.x + threadIdx.x;
    int stride = gridDim.x * blockDim.x;
    for (; i < n; i += stride) p[i] = v;
}

// -------------------- transpose + fp32->f16 (512x512): out[c][r] = in[r][c] --------------------
__global__ __launch_bounds__(256) void tcvt_kernel(const float* __restrict__ in,
                                                   _Float16* __restrict__ out) {
    __shared__ float tile[32][33];
    int bid = blockIdx.x;
    int rb = (bid >> 4) * 32, cb = (bid & 15) * 32;
    int tx = threadIdx.x & 31, ty = threadIdx.x >> 5;
    for (int rr = ty; rr < 32; rr += 8)
        tile[rr][tx] = in[(size_t)(rb + rr) * SS + cb + tx];
    __syncthreads();
    for (int rr = ty; rr < 32; rr += 8)
        out[(size_t)(cb + rr) * SS + rb + tx] = (_Float16)tile[tx][rr];
}

// -------------------- W = C0 @ B1 (512x512x512 fp32) --------------------
__global__ __launch_bounds__(256) void wmm_kernel(const float* __restrict__ C0,
                                                  const float* __restrict__ B1,
                                                  float* __restrict__ W) {
    int k = blockIdx.x;
    int tid = threadIdx.x;
    const float* crow = C0 + (size_t)k * SS;
    float s0 = 0.f, s1 = 0.f;
    for (int m = 0; m < SS; ++m) {
        float cv = crow[m];
        s0 += cv * B1[(size_t)m * SS + tid];
        s1 += cv * B1[(size_t)m * SS + tid + 256];
    }
    W[(size_t)k * SS + tid] = s0;
    W[(size_t)k * SS + tid + 256] = s1;
}

// -------------------- big GEMM: M=32768, N=512, K=512 --------------------
// BT: f16 [n][k]. ALAY 0: A fp32 [m][k] (m=b*2048+t). ALAY 1: A f16 hex layout [t][b][k].
// MODE 0: U f16 scan layout [t][g][c(16)][b(16)]; MODE 1: fp32 out[m][n].
template <int ALAY, int MODE>
__global__ __launch_bounds__(256) void gemm_kernel(const void* __restrict__ Aptr,
                                                   const _Float16* __restrict__ BT,
                                                   void* __restrict__ Outp) {
    int lane = threadIdx.x & 63;
    int wv   = threadIdx.x >> 6;
    int wid  = blockIdx.x * 4 + wv;
    int mt   = wid >> 3;
    int nb   = (wid & 7) * 64;
    int mbase = mt * 16;
    int lo = lane & 15, q = lane >> 4;

    f32x4 acc[4] = {{0,0,0,0},{0,0,0,0},{0,0,0,0},{0,0,0,0}};

    const float*    Af = (const float*)Aptr;
    const _Float16* Ah = (const _Float16*)Aptr;
    int m_row = mbase + lo;
    size_t arow = (ALAY == 1)
        ? ((size_t)(m_row & (TT - 1)) * NB + (m_row >> 11)) * SS
        : (size_t)m_row * SS;

    #pragma unroll 2
    for (int kk = 0; kk < 16; ++kk) {
        int koff = kk * 32 + q * 8;
        half8 af;
        if (ALAY == 0) {
            const float* ar = Af + arow + koff;
            f32x4 a0 = *(const f32x4*)ar;
            f32x4 a1 = *(const f32x4*)(ar + 4);
            #pragma unroll
            for (int j = 0; j < 4; ++j) { af[j] = (_Float16)a0[j]; af[4 + j] = (_Float16)a1[j]; }
        } else {
            af = *(const half8*)(Ah + arow + koff);
        }
        #pragma unroll
        for (int j = 0; j < 4; ++j) {
            int n = nb + j * 16 + lo;
            half8 bf = *(const half8*)(BT + (size_t)n * SS + koff);
            acc[j] = __builtin_amdgcn_mfma_f32_16x16x32_f16(af, bf, acc[j], 0, 0, 0);
        }
    }

    #pragma unroll
    for (int j = 0; j < 4; ++j) {
        #pragma unroll
        for (int i = 0; i < 4; ++i) {
            int m = mbase + q * 4 + i;
            int n = nb + j * 16 + lo;
            if (MODE == 0) {
                int b = m >> 11, t = m & (TT - 1);
                int gg = n >> 4, cc = n & 15;
                ((_Float16*)Outp)[((size_t)t * NCH + gg) * 256 + cc * 16 + b] = (_Float16)acc[j][i];
            } else {
                ((float*)Outp)[(size_t)m * SS + n] = acc[j][i];
            }
        }
    }
}

// -------------------- distributed liquid scan --------------------
// 32 WGs x 64 threads (1 wave each; all co-resident on 256 CUs).
// WG g owns columns [g*16, g*16+16); A,K column slices live in VGPRs.
// Sync protocol (NO agent fences -- only vmcnt + one-word counters):
//   stats: f32 atomic adds -> s_waitcnt vmcnt(0) -> scnt[t]++ ; consumers spin scnt==32.
//   h:     u32 atomic stores -> s_waitcnt vmcnt(0) -> hcnt[t]++ ; consumers spin hcnt==32.
// All cross-WG data read/written with agent-scope relaxed atomics (sc-coherent).
__global__ __launch_bounds__(64, 1) void scan_kernel(const _Float16* __restrict__ U,
                                                     const _Float16* __restrict__ AT,
                                                     const _Float16* __restrict__ KT,
                                                     const float* __restrict__ ab,
                                                     const float* __restrict__ gn,
                                                     const float* __restrict__ bt,
                                                     unsigned int* __restrict__ hex,
                                                     float* __restrict__ stats,
                                                     int* __restrict__ scnt,
                                                     int* __restrict__ hcnt) {
    const int g  = blockIdx.x;
    const int l  = threadIdx.x;
    const int lo = l & 15;
    const int q  = l >> 4;

    // weights resident in VGPRs (B-operand frags: col = g*16+lo, k = kk*32 + q*8 + j)
    half8 afr[16], kfr[16];
    #pragma unroll
    for (int kk = 0; kk < 16; ++kk) {
        afr[kk] = *(const half8*)(AT + (size_t)(g * 16 + lo) * SS + kk * 32 + q * 8);
        kfr[kk] = *(const half8*)(KT + (size_t)(g * 16 + lo) * SS + kk * 32 + q * 8);
    }

    const float ab_c = ab[g * 16 + lo];
    const float g_c  = gn[g * 16 + lo];
    const float bt_c = bt[g * 16 + lo];

    float h_own[4] = {0.f, 0.f, 0.f, 0.f};
    float up[4]    = {0.f, 0.f, 0.f, 0.f};
    int alive = 1;

    for (int t = 0; t < TT; ++t) {
        // ---- this step's u slice (prior-kernel data: plain load is safe) ----
        ull uw = *(const ull*)(U + ((size_t)t * NCH + g) * 256 + lo * 16 + q * 4);
        float u4[4];
        #pragma unroll
        for (int i = 0; i < 4; ++i)
            u4[i] = (float)__builtin_bit_cast(_Float16, (unsigned short)(uw >> (16 * i)));

        f32x4 accA0 = {0,0,0,0}, accA1 = {0,0,0,0};
        f32x4 accK0 = {0,0,0,0}, accK1 = {0,0,0,0};

        if (t > 0) {
            // ---- wait for h[t-1] (single-word spin) ----
            int it = 0;
            while (alive) {
                if (__hip_atomic_load(hcnt + (t - 1), __ATOMIC_RELAXED, SCOPE_AGENT) >= NCH) break;
                if (++it > SPIN_BOUND) alive = 0;
            }
            asm volatile("" ::: "memory");
            // ---- load h frags (agent-scope atomic u64 loads; 32 total) ----
            const ull* hb = (const ull*)hex + ((size_t)(t - 1) * NB + lo) * (SS / 4) + q * 2;
            ull hbuf[32];
            #pragma unroll
            for (int kk = 0; kk < 16; ++kk) {
                hbuf[2 * kk]     = __hip_atomic_load(hb + (size_t)kk * 8,     __ATOMIC_RELAXED, SCOPE_AGENT);
                hbuf[2 * kk + 1] = __hip_atomic_load(hb + (size_t)kk * 8 + 1, __ATOMIC_RELAXED, SCOPE_AGENT);
            }
            #pragma unroll
            for (int kk = 0; kk < 16; ++kk) {
                union { ull u[2]; half8 h; } cv;
                cv.u[0] = hbuf[2 * kk];
                cv.u[1] = hbuf[2 * kk + 1];
                if (kk & 1) {
                    accA1 = __builtin_amdgcn_mfma_f32_16x16x32_f16(cv.h, afr[kk], accA1, 0, 0, 0);
                    accK1 = __builtin_amdgcn_mfma_f32_16x16x32_f16(cv.h, kfr[kk], accK1, 0, 0, 0);
                } else {
                    accA0 = __builtin_amdgcn_mfma_f32_16x16x32_f16(cv.h, afr[kk], accA0, 0, 0, 0);
                    accK0 = __builtin_amdgcn_mfma_f32_16x16x32_f16(cv.h, kfr[kk], accK0, 0, 0, 0);
                }
            }
        }

        // ---- z slice (C-layout: row q*4+i = batch, col lo) ----
        float z[4], s1[4], s2[4];
        #pragma unroll
        for (int i = 0; i < 4; ++i) {
            z[i] = (accA0[i] + accA1[i]) + u4[i] + ab_c + (accK0[i] + accK1[i]) * up[i];
            s1[i] = z[i];
            s2[i] = z[i] * z[i];
        }

        // ---- partial sums over this chunk's 16 cols (butterfly in lo bits) ----
        #pragma unroll
        for (int off = 1; off < 16; off <<= 1) {
            #pragma unroll
            for (int i = 0; i < 4; ++i) {
                s1[i] += __shfl_xor(s1[i], off, 64);
                s2[i] += __shfl_xor(s2[i], off, 64);
            }
        }

        // ---- publish stats (f32 atomic adds), then vmcnt-ordered arrival ----
        if (lo == 0) {
            #pragma unroll
            for (int i = 0; i < 4; ++i) {
                __hip_atomic_fetch_add(stats + ((size_t)t * NB + q * 4 + i) * 2 + 0, s1[i], __ATOMIC_RELAXED, SCOPE_AGENT);
                __hip_atomic_fetch_add(stats + ((size_t)t * NB + q * 4 + i) * 2 + 1, s2[i], __ATOMIC_RELAXED, SCOPE_AGENT);
            }
        }
        asm volatile("s_waitcnt vmcnt(0)" ::: "memory");
        if (l == 0) __hip_atomic_fetch_add(scnt + t, 1, __ATOMIC_RELAXED, SCOPE_AGENT);

        // ---- wait for all stats (single-word spin), then read them ----
        {
            int it = 0;
            while (alive) {
                if (__hip_atomic_load(scnt + t, __ATOMIC_RELAXED, SCOPE_AGENT) >= NCH) break;
                if (++it > SPIN_BOUND) alive = 0;
            }
            asm volatile("" ::: "memory");
        }
        float S1x[4], S2x[4];
        #pragma unroll
        for (int i = 0; i < 4; ++i) {
            unsigned a = __hip_atomic_load((unsigned*)stats + ((size_t)t * NB + q * 4 + i) * 2 + 0, __ATOMIC_RELAXED, SCOPE_AGENT);
            unsigned b2 = __hip_atomic_load((unsigned*)stats + ((size_t)t * NB + q * 4 + i) * 2 + 1, __ATOMIC_RELAXED, SCOPE_AGENT);
            S1x[i] = bits2f(a); S2x[i] = bits2f(b2);
        }

        // ---- LN + exact GELU + state update + publish h ----
        #pragma unroll
        for (int i = 0; i < 4; ++i) {
            float mu  = S1x[i] * (1.0f / SS);
            float var = S2x[i] * (1.0f / SS) - mu * mu;
            float rs  = rsqrtf(var + 1e-5f);
            float zn  = (z[i] - mu) * rs * g_c + bt_c;
            float d   = 0.5f * zn * (1.0f + erff(zn * 0.70710678118654752f));
            h_own[i] += d;
            unsigned short hb16 = __builtin_bit_cast(unsigned short, (_Float16)h_own[i]);
            int pr = __shfl_xor((int)hb16, 1, 64);
            if (!(lo & 1)) {
                unsigned word = ((unsigned)hb16 & 0xFFFFu) | ((unsigned)pr << 16);
                __hip_atomic_store(hex + ((size_t)t * NB + q * 4 + i) * 256 + g * 8 + (lo >> 1),
                                   word, __ATOMIC_RELAXED, SCOPE_AGENT);
            }
            up[i] = u4[i];
        }
        asm volatile("s_waitcnt vmcnt(0)" ::: "memory");
        if (l == 0) __hip_atomic_fetch_add(hcnt + t, 1, __ATOMIC_RELAXED, SCOPE_AGENT);
    }
}

// -------------------- host launch --------------------
extern "C" void kernel_launch(void* const* d_in, const int* in_sizes, int n_in,
                              void* d_out, int out_size, void* d_ws, size_t ws_size,
                              hipStream_t stream) {
    const float* x   = (const float*)d_in[0];
    const float* A0  = (const float*)d_in[1];
    const float* B0  = (const float*)d_in[2];
    const float* C0  = (const float*)d_in[3];
    const float* K0  = (const float*)d_in[4];
    const float* ab0 = (const float*)d_in[5];
    const float* g0  = (const float*)d_in[6];
    const float* bt0 = (const float*)d_in[7];
    const float* A1  = (const float*)d_in[8];
    const float* B1  = (const float*)d_in[9];
    const float* C1  = (const float*)d_in[10];
    const float* K1  = (const float*)d_in[11];
    const float* ab1 = (const float*)d_in[12];
    const float* g1  = (const float*)d_in[13];
    const float* bt1 = (const float*)d_in[14];

    char* ws = (char*)d_ws;
    size_t off = 0;
    auto alloc = [&](size_t bytes) { size_t o = off; off = (off + bytes + 255) & ~(size_t)255; return o; };

    const size_t U_BYTES   = (size_t)TT * NCH * 256 * 2;    // 33.5 MB f16
    const size_t HEX_BYTES = (size_t)TT * NB * SS * 2;      // 33.5 MB f16
    const size_t ST_BYTES  = (size_t)TT * NB * 2 * 4;       // 256 KB f32
    const size_t CN_BYTES  = (size_t)TT * 4;                // 8 KB
    const size_t WT_BYTES  = (size_t)SS * SS * 2;

    _Float16*     U0   = (_Float16*)(ws + alloc(U_BYTES));
    _Float16*     U1   = (_Float16*)(ws + alloc(U_BYTES));
    unsigned int* hex0 = (unsigned int*)(ws + alloc(HEX_BYTES));
    unsigned int* hex1 = (unsigned int*)(ws + alloc(HEX_BYTES));
    // contiguous zero region: st0, st1, scnt0, hcnt0, scnt1, hcnt1
    char* zbase = ws + alloc(2 * ST_BYTES + 4 * CN_BYTES);
    float* st0   = (float*)zbase;
    float* st1   = (float*)(zbase + ST_BYTES);
    int*   scnt0 = (int*)(zbase + 2 * ST_BYTES);
    int*   hcnt0 = scnt0 + TT;
    int*   scnt1 = hcnt0 + TT;
    int*   hcnt1 = scnt1 + TT;
    _Float16* AT0 = (_Float16*)(ws + alloc(WT_BYTES));
    _Float16* KT0 = (_Float16*)(ws + alloc(WT_BYTES));
    _Float16* AT1 = (_Float16*)(ws + alloc(WT_BYTES));
    _Float16* KT1 = (_Float16*)(ws + alloc(WT_BYTES));
    _Float16* B0T = (_Float16*)(ws + alloc(WT_BYTES));
    _Float16* WT  = (_Float16*)(ws + alloc(WT_BYTES));
    _Float16* C1T = (_Float16*)(ws + alloc(WT_BYTES));
    float*    Wf  = (float*)(ws + alloc((size_t)SS * SS * 4));

    // 1) zero stats + counters
    int nz = (int)((2 * ST_BYTES + 4 * CN_BYTES) / 4);
    fill_kernel<<<128, 256, 0, stream>>>((unsigned int*)zbase, 0u, nz);

    // 2) weight transposes/converts
    tcvt_kernel<<<256, 256, 0, stream>>>(A0, AT0);
    tcvt_kernel<<<256, 256, 0, stream>>>(K0, KT0);
    tcvt_kernel<<<256, 256, 0, stream>>>(A1, AT1);
    tcvt_kernel<<<256, 256, 0, stream>>>(K1, KT1);
    tcvt_kernel<<<256, 256, 0, stream>>>(B0, B0T);
    tcvt_kernel<<<256, 256, 0, stream>>>(C1, C1T);

    // 3) W = C0 @ B1 (layer fold)
    wmm_kernel<<<512, 256, 0, stream>>>(C0, B1, Wf);
    tcvt_kernel<<<256, 256, 0, stream>>>(Wf, WT);

    // 4) U0 = x @ B0
    gemm_kernel<0, 0><<<4096, 256, 0, stream>>>((const void*)x, B0T, (void*)U0);

    // 5) layer-0 scan
    scan_kernel<<<NCH, 64, 0, stream>>>(U0, AT0, KT0, ab0, g0, bt0, hex0, st0, scnt0, hcnt0);

    // 6) U1 = h0 @ (C0@B1)
    gemm_kernel<1, 0><<<4096, 256, 0, stream>>>((const void*)hex0, WT, (void*)U1);

    // 7) layer-1 scan
    scan_kernel<<<NCH, 64, 0, stream>>>(U1, AT1, KT1, ab1, g1, bt1, hex1, st1, scnt1, hcnt1);

    // 8) out = h1 @ C1
    gemm_kernel<1, 1><<<4096, 256, 0, stream>>>((const void*)hex1, C1T, d_out);
}